// Round 16
// baseline (207.400 us; speedup 1.0000x reference)
//
#include <hip/hip_runtime.h>

#define NPTS 65536          // B*N = 32*2048
#define HH 256
#define DIN 131
#define LAT 128
#define STEPS 5
#define DT 0.2f

typedef unsigned int uint;
typedef unsigned short ushort;
typedef __attribute__((ext_vector_type(8))) short short8;
typedef __attribute__((ext_vector_type(4))) float floatx4;
typedef __attribute__((ext_vector_type(4))) uint uintx4;

// Dynamic LDS layout (158208 B total):
//   smWsw   @ 0      : 131072 B  W2 bf16 fragments (MFMA A operand)
//   smW1tab @ 131072 :  23040 B  [s][kt][q] groups of 8 unit-records {wa,wc,ra,ba_s} (16B),
//                                group stride 144B (pad -> the 4 quads hit distinct banks)
//   smW3    @ 154112 :   3072 B  SoA per (nt,q): {w30[4]}{w31[4]}{b2[4]} (3 x b128)
#define OFF_W1TAB 131072
#define OFF_W3    154112
#define LDS_TOTAL 158208

__device__ __forceinline__ float tanh_fast(float x) {
    // tanh(x) = 1 - 2/(exp2(2x*log2e)+1); exact at both saturated ends.
    float e = __builtin_amdgcn_exp2f(x * 2.8853900817779268f);
    return 1.0f - 2.0f * __builtin_amdgcn_rcpf(e + 1.0f);
}

__device__ __forceinline__ ushort f2bf(float f) {
    uint u = __builtin_bit_cast(uint, f);
    u += 0x7fffu + ((u >> 16) & 1u);   // RNE
    return (ushort)(u >> 16);
}

// pack two f32 -> 2x bf16 (RNE) in one instruction; lo -> bits[15:0]
__device__ __forceinline__ uint cvt_pk_bf16(float lo, float hi) {
    uint r;
    asm("v_cvt_pk_bf16_f32 %0, %1, %2" : "=v"(r) : "v"(lo), "v"(hi));
    return r;
}

// ---- prep (r10/r15-identical, correctness-verified):
//  a1[b][h] = b1[h] + sum_l z[b][l]*W1[h][3+l]   (t=0 bias)
//  rs[h] = sum_l W1[h][3+l]
//  wsw[((nt*8+kt)*64+lane)*8+j] = W2[nt*16+(lane&15)][kt*32+(lane>>4)*8+j]
__global__ void prep_kernel(const float* __restrict__ z, const float* __restrict__ W1,
                            const float* __restrict__ b1, const float* __restrict__ W2,
                            float* __restrict__ a1, float* __restrict__ rsv,
                            ushort* __restrict__ wsw)
{
    int tid = blockIdx.x * 256 + threadIdx.x;
    if (tid < 8192) {
        int b = tid >> 8, h = tid & 255;
        const float* wrow = W1 + h * DIN;
        const float* zb = z + b * LAT;
        float s = b1[h], r = 0.f;
        for (int l = 0; l < LAT; ++l) { float wv = wrow[3 + l]; s += wv * zb[l]; r += wv; }
        a1[tid] = s;
        if (b == 0) rsv[h] = r;
    } else {
        int t = tid - 8192;                    // 0..8191
        int lane = t & 63, kt = (t >> 6) & 7, nt = t >> 9;
        int n = nt * 16 + (lane & 15);
        int k = kt * 32 + (lane >> 4) * 8;
        const float* src = W2 + n * HH + k;
        ushort* dst = wsw + t * 8;
        #pragma unroll
        for (int j = 0; j < 8; ++j) dst[j] = f2bf(src[j]);
    }
}

// r16 = r15 champion (161us cnf / 206us total; barrier-free wave-complete,
// all-LDS weights, setprio'd MFMA clusters) + two safe trims:
//  (A) grid 512->256 blocks; each block loops over 2 point-batches in-kernel,
//      REUSING the staged 128KB W2 + tables (both batches share the same b).
//      Saves one full staging round + one launch round per CU.
//  (B) W3 table repacked SoA per (nt,q): {w30[4]}{w31[4]}{b2[4]} -> 3 ds_read_b128
//      per (pass,n2) instead of 4 (LDS is the co-dominant pipe at ~57%).
__global__ __launch_bounds__(512, 2) void cnf_kernel(
        const float* __restrict__ xin, const float* __restrict__ W1,
        const float* __restrict__ b2, const float* __restrict__ W3,
        const float* __restrict__ b3, const float* __restrict__ osc,
        const float* __restrict__ a1, const float* __restrict__ rsv,
        const ushort* __restrict__ wsw, float* __restrict__ out)
{
    extern __shared__ __align__(16) char sm[];

    const int tid = threadIdx.x;
    const int lane = tid & 63;
    const int w = tid >> 6;                      // 8 independent waves
    const int r15 = lane & 15;
    const int q = lane >> 4;
    const int blk = blockIdx.x;
    const int b = blk >> 3;                      // 8 blocks per batch-row (256 pts/block)

    // ---- stage W2 fragments: linear 131072B copy ----
    {
        uintx4* dst = (uintx4*)sm;
        const uintx4* src = (const uintx4*)wsw;
        #pragma unroll
        for (int i = 0; i < 16; ++i) dst[tid + i * 512] = src[tid + i * 512];
    }
    // ---- stage per-step layer-1 records + W3 SoA projection table ----
    if (tid < HH) {
        const int h = tid;
        const int kt = h >> 5, rem = h & 31, qq = rem >> 3, u = rem & 7;
        const float wa = W1[h * DIN + 0];
        const float wc = W1[h * DIN + 1];
        const float wt = W1[h * DIN + 2];
        const float ra = rsv[h];
        const float ba = a1[b * HH + h];
        #pragma unroll
        for (int s = 0; s < STEPS; ++s) {
            float* rec = (float*)(sm + OFF_W1TAB + s * 4608 + kt * 576 + qq * 144 + u * 16);
            rec[0] = wa; rec[1] = wc; rec[2] = ra; rec[3] = ba + wt * ((float)s * DT);
        }
        // SoA: j = nt*16 + q*4 + r  ->  group (nt*4+q), component {0:w30,1:w31,2:b2}, slot r
        const int nt = h >> 4, qg = (h >> 2) & 3, r = h & 3;
        float* g = (float*)(sm + OFF_W3 + (size_t)(nt * 4 + qg) * 48);
        g[0 + r] = W3[h];            // w30[r]
        g[4 + r] = W3[HH + h];       // w31[r]
        g[8 + r] = b2[h];            // b2[r]
    }

    const float osdt = osc[0] * DT;
    const float b30 = b3[0], b31 = b3[1];

    __syncthreads();                             // the ONLY barrier

    const char* wtab = sm + OFF_W1TAB + q * 144; // this quad's unit records
    const char* wlo  = sm + (size_t)lane * 16;           // W2 frags, nt 0..7
    const char* whi  = sm + 65536 + (size_t)lane * 16;   // W2 frags, nt 8..15

    #pragma unroll 1
    for (int batch = 0; batch < 2; ++batch) {
        // ---- per-lane state: point (lane&15), replicated across the 4 quads ----
        const int gp = blk * 256 + batch * 128 + w * 16 + r15;
        float x0 = xin[gp * 2 + 0];
        float x1 = xin[gp * 2 + 1];
        float cc = 0.f;

        for (int s = 0; s < STEPS; ++s) {
            // ---- B-frag build (activations): 3 streams x 8 kt ----
            short8 B0[8], B1[8], B2[8];
            const char* stab = wtab + s * 4608;
            #pragma unroll
            for (int kt = 0; kt < 8; ++kt) {
                const char* kr = stab + kt * 576;
                uint p0[4], p1[4], p2[4];
                #pragma unroll
                for (int up = 0; up < 4; ++up) {
                    const float4 cA = *(const float4*)(kr + up * 32);
                    const float4 cB = *(const float4*)(kr + up * 32 + 16);
                    float pa = cA.w + cA.x * x0 + cA.y * x1 + cA.z * cc;
                    float pb = cB.w + cB.x * x0 + cB.y * x1 + cB.z * cc;
                    float ha = tanh_fast(pa), hb = tanh_fast(pb);
                    float ga = 1.f - ha * ha, gb = 1.f - hb * hb;
                    p0[up] = cvt_pk_bf16(ha, hb);
                    p1[up] = cvt_pk_bf16(ga * cA.x, gb * cB.x);
                    p2[up] = cvt_pk_bf16(ga * cA.y, gb * cB.y);
                }
                B0[kt] = __builtin_bit_cast(short8, (uintx4){p0[0], p0[1], p0[2], p0[3]});
                B1[kt] = __builtin_bit_cast(short8, (uintx4){p1[0], p1[1], p1[2], p1[3]});
                B2[kt] = __builtin_bit_cast(short8, (uintx4){p2[0], p2[1], p2[2], p2[3]});
            }

            // ---- GEMM: 8 nt-passes, acc[3][2]=24 regs; W2 A-frags from LDS ----
            float sv0 = 0.f, sv1 = 0.f, sdv = 0.f;    // per-lane (= per-point) partials
            #pragma unroll
            for (int pass = 0; pass < 8; ++pass) {
                floatx4 a0[2], a1v[2], a2[2];
                #pragma unroll
                for (int n2 = 0; n2 < 2; ++n2) {
                    a0[n2]  = (floatx4){0.f, 0.f, 0.f, 0.f};
                    a1v[n2] = (floatx4){0.f, 0.f, 0.f, 0.f};
                    a2[n2]  = (floatx4){0.f, 0.f, 0.f, 0.f};
                }
                __builtin_amdgcn_s_setprio(1);   // free-running waves: favor the MFMA phase
                #pragma unroll
                for (int kt = 0; kt < 8; ++kt) {
                    #pragma unroll
                    for (int n2 = 0; n2 < 2; ++n2) {
                        const int nt = pass * 2 + n2;
                        const char* bp = (nt < 8 ? wlo : whi) + (size_t)(((nt & 7) * 8 + kt) * 1024);
                        short8 wf = *(const short8*)bp;      // one load feeds all 3 streams
                        a0[n2]  = __builtin_amdgcn_mfma_f32_16x16x32_bf16(wf, B0[kt], a0[n2],  0, 0, 0);
                        a1v[n2] = __builtin_amdgcn_mfma_f32_16x16x32_bf16(wf, B1[kt], a1v[n2], 0, 0, 0);
                        a2[n2]  = __builtin_amdgcn_mfma_f32_16x16x32_bf16(wf, B2[kt], a2[n2],  0, 0, 0);
                    }
                }
                __builtin_amdgcn_s_setprio(0);
                // epilogue: lane's acc reg r is j = nt*16 + q*4 + r of its own point
                #pragma unroll
                for (int n2 = 0; n2 < 2; ++n2) {
                    const int nt = pass * 2 + n2;
                    const char* g = sm + OFF_W3 + (size_t)(nt * 4 + q) * 48;
                    const float4 wx = *(const float4*)(g);        // w30[r]
                    const float4 wy = *(const float4*)(g + 16);   // w31[r]
                    const float4 wb = *(const float4*)(g + 32);   // b2[r]
                    #pragma unroll
                    for (int r = 0; r < 4; ++r) {
                        float h2 = tanh_fast(a0[n2][r] + wb[r]);
                        float g2 = 1.f - h2 * h2;
                        sv0 += h2 * wx[r];
                        sv1 += h2 * wy[r];
                        sdv += g2 * (a1v[n2][r] * wx[r] + a2[n2][r] * wy[r]);
                    }
                }
            }

            // ---- cross-quad reduction (4 j-subsets) + state update, all in-wave ----
            sv0 += __shfl_xor(sv0, 16);  sv0 += __shfl_xor(sv0, 32);
            sv1 += __shfl_xor(sv1, 16);  sv1 += __shfl_xor(sv1, 32);
            sdv += __shfl_xor(sdv, 16);  sdv += __shfl_xor(sdv, 32);
            x0 += (sv0 + b30) * osdt;
            x1 += (sv1 + b31) * osdt;
            cc += sdv * osdt;
        }

        if (q == 0) {                            // one quad stores (state replicated)
            out[gp * 2 + 0] = x0;
            out[gp * 2 + 1] = x1;
            out[NPTS * 2 + gp] = cc;             // log_det
        }
    }
}

extern "C" void kernel_launch(void* const* d_in, const int* in_sizes, int n_in,
                              void* d_out, int out_size, void* d_ws, size_t ws_size,
                              hipStream_t stream) {
    const float* x   = (const float*)d_in[0];
    const float* z   = (const float*)d_in[1];
    const float* W1  = (const float*)d_in[2];
    const float* b1  = (const float*)d_in[3];
    const float* W2  = (const float*)d_in[4];
    const float* b2  = (const float*)d_in[5];
    const float* W3  = (const float*)d_in[6];
    const float* b3  = (const float*)d_in[7];
    const float* osc = (const float*)d_in[8];

    // ws layout: a1 [8192 f] @0 | rs [256 f] @32768B | wsw [65536 bf16] @33792B (~165KB)
    float* a1  = (float*)d_ws;
    float* rsv = (float*)((char*)d_ws + 32768);
    ushort* wsw = (ushort*)((char*)d_ws + 33792);

    static bool attr_set = false;
    if (!attr_set) {
        hipFuncSetAttribute((const void*)cnf_kernel,
                            hipFuncAttributeMaxDynamicSharedMemorySize, LDS_TOTAL);
        attr_set = true;
    }

    hipLaunchKernelGGL(prep_kernel, dim3(64), dim3(256), 0, stream, z, W1, b1, W2, a1, rsv, wsw);
    hipLaunchKernelGGL(cnf_kernel, dim3(256), dim3(512), LDS_TOTAL, stream,
                       x, W1, b2, W3, b3, osc, a1, rsv, wsw, (float*)d_out);
}

// Round 17
// 204.930 us; speedup vs baseline: 1.0121x; 1.0121x over previous
//
#include <hip/hip_runtime.h>

#define NPTS 65536          // B*N = 32*2048
#define HH 256
#define DIN 131
#define LAT 128
#define STEPS 5
#define DT 0.2f

typedef unsigned int uint;
typedef unsigned short ushort;
typedef __attribute__((ext_vector_type(8))) short short8;
typedef __attribute__((ext_vector_type(4))) float floatx4;
typedef __attribute__((ext_vector_type(4))) uint uintx4;

// Dynamic LDS layout (158208 B total):
//   smWsw   @ 0      : 131072 B  W2 bf16 fragments (MFMA A operand)
//   smW1tab @ 131072 :  23040 B  [s][kt][q] groups of 8 unit-records {wa,wc,ra,ba_s} (16B),
//                                group stride 144B (pad -> the 4 quads hit distinct banks)
//   smW3    @ 154112 :   3072 B  SoA per (nt,q): {w30[4]}{w31[4]}{b2[4]} (3 x b128)
#define OFF_W1TAB 131072
#define OFF_W3    154112
#define LDS_TOTAL 158208

__device__ __forceinline__ float tanh_fast(float x) {
    // tanh(x) = 1 - 2/(exp2(2x*log2e)+1); exact at both saturated ends.
    float e = __builtin_amdgcn_exp2f(x * 2.8853900817779268f);
    return 1.0f - 2.0f * __builtin_amdgcn_rcpf(e + 1.0f);
}

__device__ __forceinline__ ushort f2bf(float f) {
    uint u = __builtin_bit_cast(uint, f);
    u += 0x7fffu + ((u >> 16) & 1u);   // RNE
    return (ushort)(u >> 16);
}

// pack two f32 -> 2x bf16 (RNE) in one instruction; lo -> bits[15:0]
__device__ __forceinline__ uint cvt_pk_bf16(float lo, float hi) {
    uint r;
    asm("v_cvt_pk_bf16_f32 %0, %1, %2" : "=v"(r) : "v"(lo), "v"(hi));
    return r;
}

// ---- prep (r10/r15-identical, correctness-verified):
//  a1[b][h] = b1[h] + sum_l z[b][l]*W1[h][3+l]   (t=0 bias)
//  rs[h] = sum_l W1[h][3+l]
//  wsw[((nt*8+kt)*64+lane)*8+j] = W2[nt*16+(lane&15)][kt*32+(lane>>4)*8+j]
__global__ void prep_kernel(const float* __restrict__ z, const float* __restrict__ W1,
                            const float* __restrict__ b1, const float* __restrict__ W2,
                            float* __restrict__ a1, float* __restrict__ rsv,
                            ushort* __restrict__ wsw)
{
    int tid = blockIdx.x * 256 + threadIdx.x;
    if (tid < 8192) {
        int b = tid >> 8, h = tid & 255;
        const float* wrow = W1 + h * DIN;
        const float* zb = z + b * LAT;
        float s = b1[h], r = 0.f;
        for (int l = 0; l < LAT; ++l) { float wv = wrow[3 + l]; s += wv * zb[l]; r += wv; }
        a1[tid] = s;
        if (b == 0) rsv[h] = r;
    } else {
        int t = tid - 8192;                    // 0..8191
        int lane = t & 63, kt = (t >> 6) & 7, nt = t >> 9;
        int n = nt * 16 + (lane & 15);
        int k = kt * 32 + (lane >> 4) * 8;
        const float* src = W2 + n * HH + k;
        ushort* dst = wsw + t * 8;
        #pragma unroll
        for (int j = 0; j < 8; ++j) dst[j] = f2bf(src[j]);
    }
}

// r17 = r15 champion VERBATIM (161us cnf / 206us total: barrier-free wave-complete,
// all-LDS weights, setprio'd MFMA clusters, grid 512, VGPR 88) + trim (B) ONLY:
// W3 projection table SoA per (nt,q) -> epilogue does 3 ds_read_b128 instead of 4
// (-16 LDS reads/wave-step on the ~57%-busy LDS pipe).  r16 bundled this with the
// batch-fusion (A) which cost ~12us (1 resident block/CU either way -> HW block
// transition was already free; the in-kernel loop only perturbed regalloc).
// Single-variable A/B: if this is neutral too, r15's config is final.
__global__ __launch_bounds__(512, 2) void cnf_kernel(
        const float* __restrict__ xin, const float* __restrict__ W1,
        const float* __restrict__ b2, const float* __restrict__ W3,
        const float* __restrict__ b3, const float* __restrict__ osc,
        const float* __restrict__ a1, const float* __restrict__ rsv,
        const ushort* __restrict__ wsw, float* __restrict__ out)
{
    extern __shared__ __align__(16) char sm[];

    const int tid = threadIdx.x;
    const int lane = tid & 63;
    const int w = tid >> 6;                      // 8 independent waves
    const int r15 = lane & 15;
    const int q = lane >> 4;
    const int blk = blockIdx.x;
    const int b = blk >> 4;                      // 16 blocks per batch (128 pts/block)

    // ---- stage W2 fragments: linear 131072B copy ----
    {
        uintx4* dst = (uintx4*)sm;
        const uintx4* src = (const uintx4*)wsw;
        #pragma unroll
        for (int i = 0; i < 16; ++i) dst[tid + i * 512] = src[tid + i * 512];
    }
    // ---- stage per-step layer-1 records + W3 SoA projection table ----
    if (tid < HH) {
        const int h = tid;
        const int kt = h >> 5, rem = h & 31, qq = rem >> 3, u = rem & 7;
        const float wa = W1[h * DIN + 0];
        const float wc = W1[h * DIN + 1];
        const float wt = W1[h * DIN + 2];
        const float ra = rsv[h];
        const float ba = a1[b * HH + h];
        #pragma unroll
        for (int s = 0; s < STEPS; ++s) {
            float* rec = (float*)(sm + OFF_W1TAB + s * 4608 + kt * 576 + qq * 144 + u * 16);
            rec[0] = wa; rec[1] = wc; rec[2] = ra; rec[3] = ba + wt * ((float)s * DT);
        }
        // SoA: j = nt*16 + q*4 + r  ->  group (nt*4+q), components {w30[4]}{w31[4]}{b2[4]}
        const int nt = h >> 4, qg = (h >> 2) & 3, r = h & 3;
        float* g = (float*)(sm + OFF_W3 + (size_t)(nt * 4 + qg) * 48);
        g[0 + r] = W3[h];            // w30[r]
        g[4 + r] = W3[HH + h];       // w31[r]
        g[8 + r] = b2[h];            // b2[r]
    }

    // ---- per-lane state: point (lane&15), replicated across the 4 quads ----
    const int gp = blk * 128 + w * 16 + r15;
    float x0 = xin[gp * 2 + 0];
    float x1 = xin[gp * 2 + 1];
    float cc = 0.f;
    const float osdt = osc[0] * DT;
    const float b30 = b3[0], b31 = b3[1];

    __syncthreads();                             // the ONLY barrier

    const char* wtab = sm + OFF_W1TAB + q * 144; // this quad's unit records
    const char* wlo  = sm + (size_t)lane * 16;           // W2 frags, nt 0..7
    const char* whi  = sm + 65536 + (size_t)lane * 16;   // W2 frags, nt 8..15

    for (int s = 0; s < STEPS; ++s) {
        // ---- B-frag build (activations): 3 streams x 8 kt ----
        short8 B0[8], B1[8], B2[8];
        const char* stab = wtab + s * 4608;
        #pragma unroll
        for (int kt = 0; kt < 8; ++kt) {
            const char* kr = stab + kt * 576;
            uint p0[4], p1[4], p2[4];
            #pragma unroll
            for (int up = 0; up < 4; ++up) {
                const float4 cA = *(const float4*)(kr + up * 32);
                const float4 cB = *(const float4*)(kr + up * 32 + 16);
                float pa = cA.w + cA.x * x0 + cA.y * x1 + cA.z * cc;
                float pb = cB.w + cB.x * x0 + cB.y * x1 + cB.z * cc;
                float ha = tanh_fast(pa), hb = tanh_fast(pb);
                float ga = 1.f - ha * ha, gb = 1.f - hb * hb;
                p0[up] = cvt_pk_bf16(ha, hb);
                p1[up] = cvt_pk_bf16(ga * cA.x, gb * cB.x);
                p2[up] = cvt_pk_bf16(ga * cA.y, gb * cB.y);
            }
            B0[kt] = __builtin_bit_cast(short8, (uintx4){p0[0], p0[1], p0[2], p0[3]});
            B1[kt] = __builtin_bit_cast(short8, (uintx4){p1[0], p1[1], p1[2], p1[3]});
            B2[kt] = __builtin_bit_cast(short8, (uintx4){p2[0], p2[1], p2[2], p2[3]});
        }

        // ---- GEMM: 8 nt-passes, acc[3][2]=24 regs; W2 A-frags streamed from LDS ----
        float sv0 = 0.f, sv1 = 0.f, sdv = 0.f;    // per-lane (= per-point) partials
        #pragma unroll
        for (int pass = 0; pass < 8; ++pass) {
            floatx4 a0[2], a1v[2], a2[2];
            #pragma unroll
            for (int n2 = 0; n2 < 2; ++n2) {
                a0[n2]  = (floatx4){0.f, 0.f, 0.f, 0.f};
                a1v[n2] = (floatx4){0.f, 0.f, 0.f, 0.f};
                a2[n2]  = (floatx4){0.f, 0.f, 0.f, 0.f};
            }
            __builtin_amdgcn_s_setprio(1);       // free-running waves: favor the MFMA phase
            #pragma unroll
            for (int kt = 0; kt < 8; ++kt) {
                #pragma unroll
                for (int n2 = 0; n2 < 2; ++n2) {
                    const int nt = pass * 2 + n2;
                    const char* bp = (nt < 8 ? wlo : whi) + (size_t)(((nt & 7) * 8 + kt) * 1024);
                    short8 wf = *(const short8*)bp;      // one load feeds all 3 streams
                    a0[n2]  = __builtin_amdgcn_mfma_f32_16x16x32_bf16(wf, B0[kt], a0[n2],  0, 0, 0);
                    a1v[n2] = __builtin_amdgcn_mfma_f32_16x16x32_bf16(wf, B1[kt], a1v[n2], 0, 0, 0);
                    a2[n2]  = __builtin_amdgcn_mfma_f32_16x16x32_bf16(wf, B2[kt], a2[n2],  0, 0, 0);
                }
            }
            __builtin_amdgcn_s_setprio(0);
            // epilogue: lane's acc reg r is j = nt*16 + q*4 + r of its own point
            #pragma unroll
            for (int n2 = 0; n2 < 2; ++n2) {
                const int nt = pass * 2 + n2;
                const char* g = sm + OFF_W3 + (size_t)(nt * 4 + q) * 48;
                const float4 wx = *(const float4*)(g);        // w30[r]
                const float4 wy = *(const float4*)(g + 16);   // w31[r]
                const float4 wb = *(const float4*)(g + 32);   // b2[r]
                #pragma unroll
                for (int r = 0; r < 4; ++r) {
                    float h2 = tanh_fast(a0[n2][r] + wb[r]);
                    float g2 = 1.f - h2 * h2;
                    sv0 += h2 * wx[r];
                    sv1 += h2 * wy[r];
                    sdv += g2 * (a1v[n2][r] * wx[r] + a2[n2][r] * wy[r]);
                }
            }
        }

        // ---- cross-quad reduction (4 j-subsets) + state update, all in-wave ----
        sv0 += __shfl_xor(sv0, 16);  sv0 += __shfl_xor(sv0, 32);
        sv1 += __shfl_xor(sv1, 16);  sv1 += __shfl_xor(sv1, 32);
        sdv += __shfl_xor(sdv, 16);  sdv += __shfl_xor(sdv, 32);
        x0 += (sv0 + b30) * osdt;
        x1 += (sv1 + b31) * osdt;
        cc += sdv * osdt;
    }

    if (q == 0) {                                // one quad stores (state replicated)
        out[gp * 2 + 0] = x0;
        out[gp * 2 + 1] = x1;
        out[NPTS * 2 + gp] = cc;                 // log_det
    }
}

extern "C" void kernel_launch(void* const* d_in, const int* in_sizes, int n_in,
                              void* d_out, int out_size, void* d_ws, size_t ws_size,
                              hipStream_t stream) {
    const float* x   = (const float*)d_in[0];
    const float* z   = (const float*)d_in[1];
    const float* W1  = (const float*)d_in[2];
    const float* b1  = (const float*)d_in[3];
    const float* W2  = (const float*)d_in[4];
    const float* b2  = (const float*)d_in[5];
    const float* W3  = (const float*)d_in[6];
    const float* b3  = (const float*)d_in[7];
    const float* osc = (const float*)d_in[8];

    // ws layout: a1 [8192 f] @0 | rs [256 f] @32768B | wsw [65536 bf16] @33792B (~165KB)
    float* a1  = (float*)d_ws;
    float* rsv = (float*)((char*)d_ws + 32768);
    ushort* wsw = (ushort*)((char*)d_ws + 33792);

    static bool attr_set = false;
    if (!attr_set) {
        hipFuncSetAttribute((const void*)cnf_kernel,
                            hipFuncAttributeMaxDynamicSharedMemorySize, LDS_TOTAL);
        attr_set = true;
    }

    hipLaunchKernelGGL(prep_kernel, dim3(64), dim3(256), 0, stream, z, W1, b1, W2, a1, rsv, wsw);
    hipLaunchKernelGGL(cnf_kernel, dim3(512), dim3(512), LDS_TOTAL, stream,
                       x, W1, b2, W3, b3, osc, a1, rsv, wsw, (float*)d_out);
}